// Round 2
// baseline (409.968 us; speedup 1.0000x reference)
//
#include <hip/hip_runtime.h>
#include <hip/hip_bf16.h>

// Problem constants
#define D    1024
#define LD   64
#define NTR  8192
#define NT   8192
#define DY   128

typedef __attribute__((ext_vector_type(8))) short bf16x8;
typedef __attribute__((ext_vector_type(4))) short short4_;
typedef __attribute__((ext_vector_type(4))) float f4;

static __device__ __forceinline__ short f2bf(float f) {
    __hip_bfloat16 h = __float2bfloat16(f);
    short s; __builtin_memcpy(&s, &h, 2); return s;
}
static __device__ __forceinline__ float bf2f(short s) {
    __hip_bfloat16 h; __builtin_memcpy(&h, &s, 2); return __bfloat162float(h);
}

// ---------------------------------------------------------------------------
// K1: mu[D] = mean over rows of xtr.  64 blocks x 256 threads; each block sums
// 128 rows; thread t owns cols [4t,4t+4) -> coalesced float4; atomicAdd into mu.
// ---------------------------------------------------------------------------
__global__ __launch_bounds__(256) void mu_kernel(const float* __restrict__ xtr,
                                                 float* __restrict__ mu) {
    int c = threadIdx.x * 4;
    int r0 = blockIdx.x * 128;
    f4 acc = {0.f, 0.f, 0.f, 0.f};
    for (int r = 0; r < 128; ++r) {
        f4 v = *(const f4*)&xtr[(long)(r0 + r) * D + c];
        acc += v;
    }
    const float sc = 1.0f / (float)NTR;
    atomicAdd(&mu[c + 0], acc[0] * sc);
    atomicAdd(&mu[c + 1], acc[1] * sc);
    atomicAdd(&mu[c + 2], acc[2] * sc);
    atomicAdd(&mu[c + 3], acc[3] * sc);
}

// ---------------------------------------------------------------------------
// K2: muA[LD] = mu @ A.  1 block x 64 threads.
// ---------------------------------------------------------------------------
__global__ void muA_kernel(const float* __restrict__ mu,
                           const float* __restrict__ A,
                           float* __restrict__ muA) {
    int l = threadIdx.x;
    float s = 0.f;
    for (int k = 0; k < D; ++k) s += mu[k] * A[k * LD + l];
    muA[l] = s;
}

// ---------------------------------------------------------------------------
// K3: ytrT[DY][NTR] (bf16) = transpose of ytr[NTR][DY] (f32).  64x64 tiles.
// grid (NTR/64, DY/64) x 256 threads.
// ---------------------------------------------------------------------------
__global__ __launch_bounds__(256) void transpose_ytr(const float* __restrict__ ytr,
                                                     short* __restrict__ ytrT) {
    __shared__ float tile[64][65];
    int t0 = blockIdx.x * 64;
    int d0 = blockIdx.y * 64;
    int c = threadIdx.x & 63;
    int r4 = threadIdx.x >> 6;           // 0..3
    #pragma unroll
    for (int i = 0; i < 16; ++i) {
        int r = i * 4 + r4;
        tile[r][c] = ytr[(long)(t0 + r) * DY + d0 + c];
    }
    __syncthreads();
    #pragma unroll
    for (int i = 0; i < 16; ++i) {
        int r = i * 4 + r4;
        ytrT[(long)(d0 + r) * NTR + t0 + c] = f2bf(tile[c][r]);
    }
}

// ---------------------------------------------------------------------------
// K4: projection  q = x @ A - muA, written as bf16 hi/lo pairs.
// fp32 VALU GEMM, 64x64 tile per block, 4x4 register blocking per thread.
// grid (NT/64, 2): y==0 -> xt->qt, y==1 -> xtr->qtr.
// ---------------------------------------------------------------------------
__global__ __launch_bounds__(256) void proj_kernel(const float* __restrict__ xt,
                                                   const float* __restrict__ xtr,
                                                   const float* __restrict__ A,
                                                   const float* __restrict__ muA,
                                                   short* __restrict__ qt_hi,
                                                   short* __restrict__ qt_lo,
                                                   short* __restrict__ qtr_hi,
                                                   short* __restrict__ qtr_lo) {
    const float* x = blockIdx.y ? xtr : xt;
    short* qh = blockIdx.y ? qtr_hi : qt_hi;
    short* ql = blockIdx.y ? qtr_lo : qt_lo;

    __shared__ float xs[64 * 68];   // [row][k], pitch 68 (16B-aligned, conflict-free)
    __shared__ float as_[64 * 68];  // [k][l]

    int row0 = blockIdx.x * 64;
    int tid = threadIdx.x;
    int c0 = (tid & 15) * 4;        // output cols (l)
    int r0 = (tid >> 4) * 4;        // output rows

    f4 acc[4];
    #pragma unroll
    for (int i = 0; i < 4; ++i) acc[i] = (f4){0.f, 0.f, 0.f, 0.f};

    for (int k0 = 0; k0 < D; k0 += 64) {
        #pragma unroll
        for (int j = 0; j < 4; ++j) {
            int fi = tid + j * 256;      // 0..1023 float4 slots
            int r  = fi >> 4;            // 0..63
            int kq = fi & 15;            // 0..15
            *(f4*)&xs[r * 68 + kq * 4]  = *(const f4*)&x[(long)(row0 + r) * D + k0 + kq * 4];
            *(f4*)&as_[r * 68 + kq * 4] = *(const f4*)&A[(long)(k0 + r) * LD + kq * 4];
        }
        __syncthreads();
        #pragma unroll
        for (int kq = 0; kq < 16; ++kq) {
            f4 xv[4], av[4];
            #pragma unroll
            for (int i = 0; i < 4; ++i) xv[i] = *(const f4*)&xs[(r0 + i) * 68 + kq * 4];
            #pragma unroll
            for (int j = 0; j < 4; ++j) av[j] = *(const f4*)&as_[(kq * 4 + j) * 68 + c0];
            #pragma unroll
            for (int i = 0; i < 4; ++i) {
                #pragma unroll
                for (int j = 0; j < 4; ++j) acc[i] += xv[i][j] * av[j];
            }
        }
        __syncthreads();
    }

    f4 ma = *(const f4*)&muA[c0];
    #pragma unroll
    for (int i = 0; i < 4; ++i) {
        int row = row0 + r0 + i;
        short4_ h4, l4;
        #pragma unroll
        for (int j = 0; j < 4; ++j) {
            float qv = acc[i][j] - ma[j];
            short hi = f2bf(qv);
            h4[j] = hi;
            l4[j] = f2bf(qv - bf2f(hi));
        }
        *(short4_*)&qh[(long)row * LD + c0] = h4;
        *(short4_*)&ql[(long)row * LD + c0] = l4;
    }
}

// ---------------------------------------------------------------------------
// K5: flash attention.
// 16 query rows per block, 4-way K-split across the block's 4 waves
// (each wave streams 2048 train points in tiles of 64), then merge in LDS.
// Logits: 3-term bf16 hi/lo split MFMA (near-fp32 accuracy).
// ---------------------------------------------------------------------------
__global__ __launch_bounds__(256) void flash_kernel(const short* __restrict__ qt_hi,
                                                    const short* __restrict__ qt_lo,
                                                    const short* __restrict__ qtr_hi,
                                                    const short* __restrict__ qtr_lo,
                                                    const short* __restrict__ ytrT,
                                                    float* __restrict__ out) {
    __shared__ short ptile[4][16 * 72];       // per-wave P strip, pitch 72 (16B-aligned rows)
    __shared__ float Olds[4][16 * 128];       // per-wave O for the final merge
    __shared__ float m_s[4][16], l_s[4][16], sc_s[4][16], L_s[16];

    int tid = threadIdx.x;
    int wave = tid >> 6;
    int lane = tid & 63;
    int quad = lane >> 4;
    int l16 = lane & 15;
    int q0 = blockIdx.x * 16;

    // Q fragments (A-operand layout: row=l16, k=kk*32+quad*8+j)
    const short* qrh = qt_hi + (long)(q0 + l16) * LD + quad * 8;
    const short* qrl = qt_lo + (long)(q0 + l16) * LD + quad * 8;
    bf16x8 qh0 = *(const bf16x8*)qrh;
    bf16x8 qh1 = *(const bf16x8*)(qrh + 32);
    bf16x8 ql0 = *(const bf16x8*)qrl;
    bf16x8 ql1 = *(const bf16x8*)(qrl + 32);

    float m[4], l[4];
    f4 Ov[8];
    #pragma unroll
    for (int r = 0; r < 4; ++r) { m[r] = -1e30f; l[r] = 0.f; }
    #pragma unroll
    for (int jt = 0; jt < 8; ++jt) Ov[jt] = (f4){0.f, 0.f, 0.f, 0.f};

    short* myp = &ptile[wave][0];
    int tstart = wave * (NTR / 4);
    int tend = tstart + (NTR / 4);

    for (int t0 = tstart; t0 < tend; t0 += 64) {
        // ---- S = Q K^T for this 16x64 strip (3-term hi/lo split) ----
        f4 s[4];
        #pragma unroll
        for (int tt = 0; tt < 4; ++tt) {
            const short* kbh = qtr_hi + (long)(t0 + tt * 16 + l16) * LD + quad * 8;
            const short* kbl = qtr_lo + (long)(t0 + tt * 16 + l16) * LD + quad * 8;
            bf16x8 kh0 = *(const bf16x8*)kbh;
            bf16x8 kh1 = *(const bf16x8*)(kbh + 32);
            bf16x8 kl0 = *(const bf16x8*)kbl;
            bf16x8 kl1 = *(const bf16x8*)(kbl + 32);
            f4 acc = (f4){0.f, 0.f, 0.f, 0.f};
            acc = __builtin_amdgcn_mfma_f32_16x16x32_bf16(qh0, kh0, acc, 0, 0, 0);
            acc = __builtin_amdgcn_mfma_f32_16x16x32_bf16(ql0, kh0, acc, 0, 0, 0);
            acc = __builtin_amdgcn_mfma_f32_16x16x32_bf16(qh0, kl0, acc, 0, 0, 0);
            acc = __builtin_amdgcn_mfma_f32_16x16x32_bf16(qh1, kh1, acc, 0, 0, 0);
            acc = __builtin_amdgcn_mfma_f32_16x16x32_bf16(ql1, kh1, acc, 0, 0, 0);
            acc = __builtin_amdgcn_mfma_f32_16x16x32_bf16(qh1, kl1, acc, 0, 0, 0);
            s[tt] = acc;
        }

        // ---- online softmax (C/D layout: row=quad*4+r, col=tt*16+l16) ----
        float al[4];
        #pragma unroll
        for (int r = 0; r < 4; ++r) {
            float mx = fmaxf(fmaxf(s[0][r], s[1][r]), fmaxf(s[2][r], s[3][r]));
            mx = fmaxf(mx, __shfl_xor(mx, 1));
            mx = fmaxf(mx, __shfl_xor(mx, 2));
            mx = fmaxf(mx, __shfl_xor(mx, 4));
            mx = fmaxf(mx, __shfl_xor(mx, 8));
            float nm = fmaxf(m[r], mx);
            al[r] = __expf(m[r] - nm);
            m[r] = nm;
        }
        #pragma unroll
        for (int r = 0; r < 4; ++r) {
            float p0 = __expf(s[0][r] - m[r]);
            float p1 = __expf(s[1][r] - m[r]);
            float p2 = __expf(s[2][r] - m[r]);
            float p3 = __expf(s[3][r] - m[r]);
            short* pr = myp + (quad * 4 + r) * 72 + l16;
            pr[0]  = f2bf(p0);
            pr[16] = f2bf(p1);
            pr[32] = f2bf(p2);
            pr[48] = f2bf(p3);
            float ps = p0 + p1 + p2 + p3;
            ps += __shfl_xor(ps, 1);
            ps += __shfl_xor(ps, 2);
            ps += __shfl_xor(ps, 4);
            ps += __shfl_xor(ps, 8);
            l[r] = l[r] * al[r] + ps;
        }
        f4 alv = (f4){al[0], al[1], al[2], al[3]};
        #pragma unroll
        for (int jt = 0; jt < 8; ++jt) Ov[jt] *= alv;

        // ---- O += P V  (P via LDS round-trip into A-operand layout) ----
        #pragma unroll
        for (int kk = 0; kk < 2; ++kk) {
            bf16x8 pf = *(const bf16x8*)&myp[l16 * 72 + kk * 32 + quad * 8];
            const short* vb = ytrT + (long)l16 * NTR + t0 + kk * 32 + quad * 8;
            #pragma unroll
            for (int jt = 0; jt < 8; ++jt) {
                bf16x8 vf = *(const bf16x8*)(vb + (long)jt * 16 * NTR);
                Ov[jt] = __builtin_amdgcn_mfma_f32_16x16x32_bf16(pf, vf, Ov[jt], 0, 0, 0);
            }
        }
    }

    // ---- merge the 4 K-splits ----
    if (l16 == 0) {
        #pragma unroll
        for (int r = 0; r < 4; ++r) {
            m_s[wave][quad * 4 + r] = m[r];
            l_s[wave][quad * 4 + r] = l[r];
        }
    }
    #pragma unroll
    for (int jt = 0; jt < 8; ++jt) {
        #pragma unroll
        for (int r = 0; r < 4; ++r) {
            Olds[wave][(quad * 4 + r) * 128 + jt * 16 + l16] = Ov[jt][r];
        }
    }
    __syncthreads();
    if (tid < 16) {
        int row = tid;
        float M = m_s[0][row];
        M = fmaxf(M, m_s[1][row]);
        M = fmaxf(M, m_s[2][row]);
        M = fmaxf(M, m_s[3][row]);
        float L = 0.f;
        #pragma unroll
        for (int w = 0; w < 4; ++w) {
            float sc = __expf(m_s[w][row] - M);
            sc_s[w][row] = sc;
            L += l_s[w][row] * sc;
        }
        L_s[row] = L;
    }
    __syncthreads();
    #pragma unroll
    for (int i = 0; i < 8; ++i) {
        int idx = tid + i * 256;            // 0..2047
        int row = idx >> 7;
        int dy = idx & 127;
        float v = 0.f;
        #pragma unroll
        for (int w = 0; w < 4; ++w) v += Olds[w][row * 128 + dy] * sc_s[w][row];
        out[(long)(q0 + row) * DY + dy] = v / L_s[row];
    }
}

// ---------------------------------------------------------------------------
extern "C" void kernel_launch(void* const* d_in, const int* in_sizes, int n_in,
                              void* d_out, int out_size, void* d_ws, size_t ws_size,
                              hipStream_t stream) {
    const float* xtr = (const float*)d_in[0];   // [NTR, D]
    const float* ytr = (const float*)d_in[1];   // [NTR, DY]
    const float* xt  = (const float*)d_in[2];   // [NT, D]
    const float* A   = (const float*)d_in[3];   // [D, LD]
    float* out = (float*)d_out;                 // [NT, DY]

    // workspace carving (256B aligned)
    char* w = (char*)d_ws;
    float* mu  = (float*)w;  w += 4096;                       // D f32
    float* muA = (float*)w;  w += 256;                        // LD f32
    short* qt_hi  = (short*)w; w += (size_t)NT * LD * 2;      // 1 MB
    short* qt_lo  = (short*)w; w += (size_t)NT * LD * 2;
    short* qtr_hi = (short*)w; w += (size_t)NTR * LD * 2;
    short* qtr_lo = (short*)w; w += (size_t)NTR * LD * 2;
    short* ytrT   = (short*)w; w += (size_t)DY * NTR * 2;     // 2 MB
    (void)ws_size; (void)in_sizes; (void)n_in; (void)out_size;

    hipMemsetAsync(mu, 0, 4096, stream);
    mu_kernel<<<64, 256, 0, stream>>>(xtr, mu);
    muA_kernel<<<1, 64, 0, stream>>>(mu, A, muA);
    transpose_ytr<<<dim3(NTR / 64, DY / 64), 256, 0, stream>>>(ytr, ytrT);
    proj_kernel<<<dim3(NT / 64, 2), 256, 0, stream>>>(xt, xtr, A, muA,
                                                      qt_hi, qt_lo, qtr_hi, qtr_lo);
    flash_kernel<<<NT / 16, 256, 0, stream>>>(qt_hi, qt_lo, qtr_hi, qtr_lo, ytrT, out);
}